// Round 8
// baseline (352.747 us; speedup 1.0000x reference)
//
#include <hip/hip_runtime.h>
#include <stdint.h>

// ---------- types ----------
typedef __bf16 bf16x8 __attribute__((ext_vector_type(8)));
typedef __bf16 bf16x2 __attribute__((ext_vector_type(2)));
typedef float  f32x4  __attribute__((ext_vector_type(4)));
typedef unsigned short u16x4 __attribute__((ext_vector_type(4)));
typedef unsigned short u16x8 __attribute__((ext_vector_type(8)));

#define DEVI __device__ __forceinline__

// problem constants
constexpr int Bc = 4, Hc = 16, Ss = 2048, Dd = 128;
constexpr int BH = Bc * Hc;          // 64 heads
constexpr int BM = 256;              // q-rows per workgroup (8 waves x 32 rows)
constexpr int MT = 2;                // 16-row fragments per wave
constexpr int NW = 8;                // waves per block (512 threads)
constexpr int BN = 32;               // keys per K-tile (double-buffered)
constexpr int NTIL = Ss / BN;        // 64 tiles
// scale folds in log2(e): e^(qk/128) = 2^((qk*log2e)/128)
constexpr float SCALE = 1.44269504088896340736f / 128.0f;

constexpr int TILE_B = BN * Dd * 2;  // 8192 B
constexpr int SK_OFF = 0;            // 2 buffers x 8 KiB (K tiles, key-PERMUTED rows)
constexpr int SV_OFF = 2 * TILE_B;   // 2 buffers x 8 KiB (V^T tiles)
constexpr int LDS_BYTES = 4 * TILE_B;   // 32768 B -- in-register softmax, no sP

DEVI unsigned short f2bf_bits(float x) {
  unsigned u = __builtin_bit_cast(unsigned, x);
  u += 0x7fffu + ((u >> 16) & 1u);          // round-to-nearest-even
  return (unsigned short)(u >> 16);
}
DEVI __bf16 f2bf(float x) {
  unsigned short b = f2bf_bits(x);
  return __builtin_bit_cast(__bf16, b);
}
// pack two fp32 -> dword of 2 bf16 (compiler emits v_cvt_pk_bf16_f32)
DEVI unsigned pk2(float a, float b) {
  bf16x2 t; t[0] = (__bf16)a; t[1] = (__bf16)b;
  return __builtin_bit_cast(unsigned, t);
}

// hardware 2^x (v_exp_f32)
DEVI float exp2_hw(float x) { return __builtin_amdgcn_exp2f(x); }

// async global->LDS, 16B per lane; LDS dest = wave-uniform base + lane*16
DEVI void gload_lds16(const void* g, void* l) {
  __builtin_amdgcn_global_load_lds(
      (const __attribute__((address_space(1))) unsigned*)(uintptr_t)g,
      (__attribute__((address_space(3))) unsigned*)(unsigned)(uintptr_t)l,
      16, 0, 0);
}

// ---------------- fused pre-pass (unchanged, measured-good) ----------------
constexpr int LDT2 = 136;
__global__ void k_prep(const float* __restrict__ kin, __bf16* __restrict__ kout,
                       const float* __restrict__ v, __bf16* __restrict__ vt) {
  __shared__ __align__(16) unsigned short tile[64 * LDT2];
  const int bx = blockIdx.x;
  const int u = threadIdx.x;
  if (bx >= 2048) {
    constexpr int N4 = (BH * Ss * Dd) / 4;
    int i = (bx - 2048) * 256 + u;
    const int stride = 2048 * 256;
    #pragma unroll
    for (int it = 0; it < N4 / (2048 * 256); it++, i += stride) {
      float4 x = ((const float4*)kin)[i];
      ushort4 o;
      o.x = f2bf_bits(x.x); o.y = f2bf_bits(x.y);
      o.z = f2bf_bits(x.z); o.w = f2bf_bits(x.w);
      ((ushort4*)kout)[i] = o;
    }
    return;
  }
  const int bh = bx >> 5;
  const int s0 = (bx & 31) * 64;
  const float4* src = (const float4*)(v + ((size_t)bh * Ss + s0) * Dd);
  #pragma unroll
  for (int i = 0; i < 8; i++) {
    int f = i * 256 + u;
    int row = f >> 5;
    int c4 = (f & 31) << 2;
    float4 x = src[f];
    u16x4 o;
    o[0] = f2bf_bits(x.x); o[1] = f2bf_bits(x.y);
    o[2] = f2bf_bits(x.z); o[3] = f2bf_bits(x.w);
    *(u16x4*)&tile[row * LDT2 + c4] = o;
  }
  __syncthreads();
  const int so = u & 7;
  const int dq = u >> 3;
  u16x4 tin[8];
  #pragma unroll
  for (int i = 0; i < 8; i++)
    tin[i] = *(const u16x4*)&tile[(so * 8 + i) * LDT2 + dq * 4];
  #pragma unroll
  for (int j = 0; j < 4; j++) {
    u16x8 o;
    #pragma unroll
    for (int i = 0; i < 8; i++) o[i] = tin[i][j];
    *(u16x8*)(vt + ((size_t)bh * Dd + dq * 4 + j) * Ss + s0 + so * 8) = o;
  }
}

// ---------------- flash attention ----------------
// grid: 512 = 8 q-tiles x 64 heads; 512-thread blocks (8 waves x 32 q-rows).
// 2 blocks/CU x 8 waves = 16 waves/CU (4/SIMD) -- doubled TLP vs 4-wave mt=4
// to fill the serial QK^T->exp->PV chain's stalls. In-register softmax via
// key-permuted K staging (R7, verified): S^T slot (nt,quad,r) = actual key
// 8*quad + 4*nt + r, so each lane's exp'd scores ARE its PV A-fragment.
__launch_bounds__(512, 4)
__global__ void k_flash(const float* __restrict__ Q, const __bf16* __restrict__ Kb,
                        const __bf16* __restrict__ Vt, float* __restrict__ O) {
  __shared__ __align__(16) char lds[LDS_BYTES];

  const int tid = threadIdx.x;
  const int w = tid >> 6;           // wave 0..7, owns q-rows [32w, 32w+32)
  const int lane = tid & 63;
  const int quad = lane >> 4;
  const int l16 = lane & 15;

  const int bx = blockIdx.x;
  const int bh = bx & (BH - 1);
  const int q0 = (bx >> 6) * BM;

  // ---- Q fragments: fp32 load, scale, cvt to bf16, keep in regs ----
  bf16x8 qa[MT][4];
  {
    const float* qb = Q + ((size_t)bh * Ss + q0 + w * 32) * Dd;
    #pragma unroll
    for (int mt = 0; mt < MT; mt++)
      #pragma unroll
      for (int kk = 0; kk < 4; kk++) {
        const float* p = qb + (mt * 16 + l16) * Dd + kk * 32 + quad * 8;
        float4 a = ((const float4*)p)[0];
        float4 b = ((const float4*)p)[1];
        bf16x8 f;
        f[0] = f2bf(a.x * SCALE); f[1] = f2bf(a.y * SCALE);
        f[2] = f2bf(a.z * SCALE); f[3] = f2bf(a.w * SCALE);
        f[4] = f2bf(b.x * SCALE); f[5] = f2bf(b.y * SCALE);
        f[6] = f2bf(b.z * SCALE); f[7] = f2bf(b.w * SCALE);
        qa[mt][kk] = f;
      }
  }

  f32x4 acc[MT][8];
  #pragma unroll
  for (int mt = 0; mt < MT; mt++)
    #pragma unroll
    for (int dt = 0; dt < 8; dt++)
      acc[mt][dt] = (f32x4){0.f, 0.f, 0.f, 0.f};

  float lacc[MT] = {0.f, 0.f};

  const __bf16* kbh = Kb + (size_t)bh * Ss * Dd;   // [s][d]
  const __bf16* vbh = Vt + (size_t)bh * Ss * Dd;   // [d][s]

  // ---- per-wave stage assignment: 16 frags (8 K + 8 V), 2 per wave ----
  // waves 0-3: K frags (key-permuted rows); waves 4-7: V frags
  const char* gp[2];
  unsigned lo[2];
  int ginc;
  if (w < 4) {
    #pragma unroll
    for (int i = 0; i < 2; i++) {
      const int fk = w * 2 + i, kk = fk >> 1, nt = fk & 1;
      const int key = 8 * (l16 >> 2) + 4 * nt + (l16 & 3);
      gp[i] = (const char*)(kbh + (size_t)key * Dd + kk * 32 + quad * 8);
      lo[i] = (unsigned)(SK_OFF + fk * 1024 + lane * 16);
    }
    ginc = BN * Dd * 2;             // next K tile: +32 keys
  } else {
    #pragma unroll
    for (int i = 0; i < 2; i++) {
      const int dt = (w - 4) * 2 + i;
      gp[i] = (const char*)(vbh + (size_t)(dt * 16 + l16) * Ss + quad * 8);
      lo[i] = (unsigned)(SV_OFF + dt * 1024 + lane * 16);
    }
    ginc = BN * 2;                  // next V tile: +32 columns
  }

  // ---- prologue: stage tile 0 into buffer 0 ----
  #pragma unroll
  for (int i = 0; i < 2; i++) gload_lds16(gp[i], lds + lo[i]);
  #pragma unroll
  for (int i = 0; i < 2; i++) gp[i] += ginc;
  __syncthreads();

  unsigned cur = 0;
  for (int t = 0; t < NTIL; t++) {
    // ---- issue next-tile stage FIRST (into the other buffer) ----
    if (t < NTIL - 1) {
      const unsigned nb = (cur ^ 1u) * (unsigned)TILE_B;
      #pragma unroll
      for (int i = 0; i < 2; i++) gload_lds16(gp[i], lds + lo[i] + nb);
      #pragma unroll
      for (int i = 0; i < 2; i++) gp[i] += ginc;
    }
    const char* bK = lds + SK_OFF + cur * TILE_B;
    const char* bV = lds + SV_OFF + cur * TILE_B;

    // ---- S^T = K Q^T (permuted keys) -> exp2 -> pack to registers ----
    unsigned pp[MT][4];              // packed bf16 pairs: [nt*2 + half]
    #pragma unroll
    for (int nt = 0; nt < 2; nt++) {
      f32x4 sc[MT];
      #pragma unroll
      for (int mt = 0; mt < MT; mt++) sc[mt] = (f32x4){0.f, 0.f, 0.f, 0.f};
      __builtin_amdgcn_s_setprio(1);
      #pragma unroll
      for (int kk = 0; kk < 4; kk++) {
        bf16x8 bk = *(const bf16x8*)(bK + (kk * 2 + nt) * 1024 + lane * 16);
        #pragma unroll
        for (int mt = 0; mt < MT; mt++)
          sc[mt] = __builtin_amdgcn_mfma_f32_16x16x32_bf16(bk, qa[mt][kk], sc[mt], 0, 0, 0);
      }
      __builtin_amdgcn_s_setprio(0);
      #pragma unroll
      for (int mt = 0; mt < MT; mt++) {
        float p0 = exp2_hw(sc[mt][0]);
        float p1 = exp2_hw(sc[mt][1]);
        float p2 = exp2_hw(sc[mt][2]);
        float p3 = exp2_hw(sc[mt][3]);
        lacc[mt] += (p0 + p1) + (p2 + p3);
        pp[mt][nt * 2 + 0] = pk2(p0, p1);
        pp[mt][nt * 2 + 1] = pk2(p2, p3);
      }
    }

    // ---- O += P V entirely from registers (A = pa, B = V^T frag) ----
    bf16x8 pa[MT];
    #pragma unroll
    for (int mt = 0; mt < MT; mt++) {
      uint4 u4 = make_uint4(pp[mt][0], pp[mt][1], pp[mt][2], pp[mt][3]);
      pa[mt] = __builtin_bit_cast(bf16x8, u4);
    }
    __builtin_amdgcn_s_setprio(1);
    #pragma unroll
    for (int dt = 0; dt < 8; dt++) {
      bf16x8 bv = *(const bf16x8*)(bV + dt * 1024 + lane * 16);
      #pragma unroll
      for (int mt = 0; mt < MT; mt++)
        acc[mt][dt] = __builtin_amdgcn_mfma_f32_16x16x32_bf16(pa[mt], bv, acc[mt][dt], 0, 0, 0);
    }
    __builtin_amdgcn_s_setprio(0);

    __syncthreads();    // waves done reading buf `cur`; stage of buf^1 drained here
    cur ^= 1u;
  }

  // ---- final l reduction: sum quads, broadcast to C-layout rows ----
  float inv_l[MT][4];
  #pragma unroll
  for (int mt = 0; mt < MT; mt++) {
    float l = lacc[mt];
    l += __shfl_xor(l, 16);
    l += __shfl_xor(l, 32);
    #pragma unroll
    for (int r = 0; r < 4; r++) {
      float lr = __shfl(l, (lane & 48) | (quad * 4 + r));
      inv_l[mt][r] = 1.0f / lr;
    }
  }

  // ---- epilogue: O / l ----
  float* ob = O + ((size_t)bh * Ss + q0 + w * 32) * Dd;
  #pragma unroll
  for (int mt = 0; mt < MT; mt++)
    #pragma unroll
    for (int r = 0; r < 4; r++) {
      const float inv = inv_l[mt][r];
      const int row = mt * 16 + quad * 4 + r;
      #pragma unroll
      for (int dt = 0; dt < 8; dt++)
        ob[row * Dd + dt * 16 + l16] = acc[mt][dt][r] * inv;
    }
}

extern "C" void kernel_launch(void* const* d_in, const int* in_sizes, int n_in,
                              void* d_out, int out_size, void* d_ws, size_t ws_size,
                              hipStream_t stream) {
  const float* Q = (const float*)d_in[0];
  const float* K = (const float*)d_in[1];
  const float* V = (const float*)d_in[2];
  float* O = (float*)d_out;
  const size_t elems = (size_t)BH * Ss * Dd;   // 16,777,216
  __bf16* Kb = (__bf16*)d_ws;
  __bf16* Vt = Kb + elems;

  k_prep<<<4096, 256, 0, stream>>>(K, Kb, V, Vt);
  k_flash<<<dim3((Ss / BM) * BH), NW * 64, 0, stream>>>(Q, Kb, Vt, O);
}